// Round 1
// baseline (231.866 us; speedup 1.0000x reference)
//
#include <hip/hip_runtime.h>
#include <hip/hip_bf16.h>

// Problem constants (from reference)
#define N_NODES 100000
#define FEAT    256
#define HID     128
#define REL     2
#define BATCH   20000
#define KNEI    10

typedef short bf16x8 __attribute__((ext_vector_type(8)));
typedef float f32x4  __attribute__((ext_vector_type(4)));

__device__ __forceinline__ unsigned short f2bf(float x) {
    union { float f; unsigned u; } v; v.f = x;
    unsigned r = v.u + 0x7fffu + ((v.u >> 16) & 1u);   // RNE
    return (unsigned short)(r >> 16);
}

// ---------------------------------------------------------------------------
// Kernel 1: build collapsed weight Wcat[768][128] directly in the MFMA
// B-fragment swizzled bf16 layout.
//   Wcat rows 0:256   = W_det[0:256]
//   Wcat rows 256:512 = W_stc[0] @ W_det[256:384]
//   Wcat rows 512:768 = W_stc[1] @ W_det[384:512]
// Swizzle: Bsw[((kt*8+nt)*64 + lane)*8 + j] = Wcat[kt*32 + (lane>>4)*8 + j][nt*16 + (lane&15)]
// so each GEMM lane loads its 8 k-values as one contiguous 16B read.
// ---------------------------------------------------------------------------
__global__ __launch_bounds__(256) void prep_B(const float* __restrict__ W_stc,
                                              const float* __restrict__ W_det,
                                              unsigned short* __restrict__ Bsw) {
    int tid = blockIdx.x * 256 + threadIdx.x;          // < 768*128 = 98304
    int j    = tid & 7;
    int lane = (tid >> 3) & 63;
    int nt   = (tid >> 9) & 7;
    int kt   = tid >> 12;                              // 0..23
    int k = kt * 32 + ((lane >> 4) * 8) + j;           // 0..767
    int n = nt * 16 + (lane & 15);                     // 0..127

    float val;
    if (k < 256) {
        val = W_det[k * HID + n];
    } else {
        int rel = (k >= 512) ? 1 : 0;
        int f = k - 256 - rel * 256;
        const float* ws = W_stc + (rel * FEAT + f) * HID;        // row of W_stc[rel]
        const float* wd = W_det + (256 + rel * HID) * HID + n;   // column of W_det block
        float s = 0.f;
        #pragma unroll 8
        for (int j2 = 0; j2 < HID; ++j2) s += ws[j2] * wd[j2 * HID];
        val = s;
    }
    Bsw[tid] = f2bf(val);
}

// ---------------------------------------------------------------------------
// Kernel 2: gather + mean. One wave (64 threads) per batch element.
// Each thread owns one float4 column (16B of a 1KB feature row).
// Writes A[b][768] bf16 = [ self(256) | mean_r0/K (256) | mean_r1/K (256) ].
// ---------------------------------------------------------------------------
__global__ __launch_bounds__(64) void gather_mean(const int* __restrict__ nodes,
                                                  const int* __restrict__ neigh_idx,
                                                  const float* __restrict__ features,
                                                  unsigned short* __restrict__ A) {
    const int b = blockIdx.x;
    const int t = threadIdx.x;                 // 0..63 : float4 column
    const float4* F4 = (const float4*)features;

    const int self = nodes[b];                 // wave-uniform -> scalar load
    float4 sf = F4[(size_t)self * 64 + t];

    float4 s0 = make_float4(0.f, 0.f, 0.f, 0.f);
    float4 s1 = make_float4(0.f, 0.f, 0.f, 0.f);
    const int* idx0 = neigh_idx + (size_t)0 * BATCH * KNEI + (size_t)b * KNEI;
    const int* idx1 = neigh_idx + (size_t)1 * BATCH * KNEI + (size_t)b * KNEI;
    #pragma unroll
    for (int k = 0; k < KNEI; ++k) {
        float4 v = F4[(size_t)idx0[k] * 64 + t];
        s0.x += v.x; s0.y += v.y; s0.z += v.z; s0.w += v.w;
    }
    #pragma unroll
    for (int k = 0; k < KNEI; ++k) {
        float4 v = F4[(size_t)idx1[k] * 64 + t];
        s1.x += v.x; s1.y += v.y; s1.z += v.z; s1.w += v.w;
    }
    const float inv = 1.0f / (float)KNEI;

    ushort4* Arow = (ushort4*)(A + (size_t)b * 768);
    ushort4 p;
    p.x = f2bf(sf.x); p.y = f2bf(sf.y); p.z = f2bf(sf.z); p.w = f2bf(sf.w);
    Arow[t] = p;
    p.x = f2bf(s0.x * inv); p.y = f2bf(s0.y * inv); p.z = f2bf(s0.z * inv); p.w = f2bf(s0.w * inv);
    Arow[64 + t] = p;
    p.x = f2bf(s1.x * inv); p.y = f2bf(s1.y * inv); p.z = f2bf(s1.z * inv); p.w = f2bf(s1.w * inv);
    Arow[128 + t] = p;
}

// ---------------------------------------------------------------------------
// Kernel 3: GEMM + ReLU.  out[20000][128] = relu(A[20000][768] @ Wcat[768][128])
// One wave per 16-row M-tile, covering all 128 columns (8 n-tiles).
// A fragment: lane reads A[mtile*16 + (lane&15)][kt*32 + (lane>>4)*8 .. +8] (16B contig).
// B fragment: contiguous 16B per lane from the pre-swizzled Bsw.
// C/D layout: col = lane&15, row = (lane>>4)*4 + reg.
// ---------------------------------------------------------------------------
__global__ __launch_bounds__(256) void gemm_relu(const unsigned short* __restrict__ A,
                                                 const unsigned short* __restrict__ Bsw,
                                                 float* __restrict__ out) {
    const int wave = (blockIdx.x * 256 + threadIdx.x) >> 6;   // global m-tile id
    if (wave >= BATCH / 16) return;                           // 1250 tiles
    const int lane = threadIdx.x & 63;
    const int quad = lane >> 4;
    const int l16  = lane & 15;

    const unsigned short* arow = A + ((size_t)(wave * 16 + l16)) * 768 + quad * 8;

    f32x4 acc[8];
    #pragma unroll
    for (int nt = 0; nt < 8; ++nt) acc[nt] = (f32x4){0.f, 0.f, 0.f, 0.f};

    #pragma unroll 4
    for (int kt = 0; kt < 24; ++kt) {
        bf16x8 a = *(const bf16x8*)(arow + kt * 32);
        const unsigned short* bk = Bsw + ((size_t)(kt * 8) * 64 + lane) * 8;
        #pragma unroll
        for (int nt = 0; nt < 8; ++nt) {
            bf16x8 bfr = *(const bf16x8*)(bk + (size_t)nt * 64 * 8);
            acc[nt] = __builtin_amdgcn_mfma_f32_16x16x32_bf16(a, bfr, acc[nt], 0, 0, 0);
        }
    }

    float* orow = out + (size_t)(wave * 16) * HID;
    #pragma unroll
    for (int nt = 0; nt < 8; ++nt) {
        #pragma unroll
        for (int r = 0; r < 4; ++r) {
            int row = quad * 4 + r;
            int col = nt * 16 + l16;
            float v = acc[nt][r];
            orow[(size_t)row * HID + col] = v > 0.f ? v : 0.f;
        }
    }
}

extern "C" void kernel_launch(void* const* d_in, const int* in_sizes, int n_in,
                              void* d_out, int out_size, void* d_ws, size_t ws_size,
                              hipStream_t stream) {
    const int*   nodes     = (const int*)d_in[0];
    const int*   neigh_idx = (const int*)d_in[1];
    const float* features  = (const float*)d_in[2];
    const float* W_stc     = (const float*)d_in[3];
    const float* W_det     = (const float*)d_in[4];
    float* out = (float*)d_out;

    // Workspace layout: Bsw (768*128 bf16 = 192KB, rounded to 256KB) | A (20000*768 bf16 ~ 30.7MB)
    unsigned short* Bsw = (unsigned short*)d_ws;
    unsigned short* A   = (unsigned short*)((char*)d_ws + 256 * 1024);

    prep_B<<<(768 * 128) / 256, 256, 0, stream>>>(W_stc, W_det, Bsw);
    gather_mean<<<BATCH, 64, 0, stream>>>(nodes, neigh_idx, features, A);
    gemm_relu<<<(BATCH / 16 + 3) / 4, 256, 0, stream>>>(A, Bsw, out);
}

// Round 2
// 231.565 us; speedup vs baseline: 1.0013x; 1.0013x over previous
//
#include <hip/hip_runtime.h>
#include <hip/hip_bf16.h>

// Problem constants (from reference)
#define N_NODES 100000
#define FEAT    256
#define HID     128
#define REL     2
#define BATCH   20000
#define KNEI    10

#define APAD    8            // pad shorts per LDS A row (breaks pow-2 stride)
#define AROW    (768 + APAD) // 776 shorts = 1552 B row stride

typedef short bf16x8 __attribute__((ext_vector_type(8)));
typedef float f32x4  __attribute__((ext_vector_type(4)));

__device__ __forceinline__ unsigned short f2bf(float x) {
    union { float f; unsigned u; } v; v.f = x;
    unsigned r = v.u + 0x7fffu + ((v.u >> 16) & 1u);   // RNE
    return (unsigned short)(r >> 16);
}

__device__ __forceinline__ ushort4 pack4(float a, float b, float c, float d) {
    ushort4 p; p.x = f2bf(a); p.y = f2bf(b); p.z = f2bf(c); p.w = f2bf(d);
    return p;
}

// Swizzled B index for logical (k, n):
//   kt=k>>5, j=k&7, hi=(k>>3)&3, lane=hi*16+(n&15), nt=n>>4
//   dest = ((kt*8+nt)*64 + lane)*8 + j
__device__ __forceinline__ size_t bsw_index(int k, int n) {
    int kt = k >> 5, j = k & 7, hi = (k >> 3) & 3;
    int lane = hi * 16 + (n & 15), nt = n >> 4;
    return ((size_t)(kt * 8 + nt) * 64 + lane) * 8 + j;
}

// ---------------------------------------------------------------------------
// prep_B: build collapsed weight into MFMA-swizzled bf16 layout.
// blocks 0..31  : Wcat[256+rel*256 + f][n] = dot(W_stc[rel][f][:], W_det[256+rel*128:...][n])
//                 (per block: 16 f-rows x 128 n; wd reads coalesced across lanes)
// blocks 32..33 : straight copy of W_det rows 0..255 (coalesced reads)
// ---------------------------------------------------------------------------
__global__ __launch_bounds__(256) void prep_B(const float* __restrict__ W_stc,
                                              const float* __restrict__ W_det,
                                              unsigned short* __restrict__ Bsw) {
    const int blk = blockIdx.x;
    const int tid = threadIdx.x;
    if (blk < 32) {
        const int rel   = blk >> 4;
        const int fbase = (blk & 15) * 16;
        const int n     = tid & 127;
        const int fh    = tid >> 7;              // 0..1
        const float* wd = W_det + (size_t)(256 + rel * HID) * HID + n;  // column base
        #pragma unroll
        for (int fo = 0; fo < 8; ++fo) {
            const int f = fbase + fh * 8 + fo;
            const float* ws = W_stc + (size_t)(rel * FEAT + f) * HID;
            float acc = 0.f;
            #pragma unroll 8
            for (int j2 = 0; j2 < HID; ++j2) acc += ws[j2] * wd[(size_t)j2 * HID];
            const int k = 256 + rel * 256 + f;
            Bsw[bsw_index(k, n)] = f2bf(acc);
        }
    } else {
        const int base = (blk - 32) * 16384;     // 2 blocks x 16384 elems
        #pragma unroll 4
        for (int i = 0; i < 64; ++i) {
            const int idx = base + i * 256 + tid;  // < 32768
            const int k = idx >> 7, n = idx & 127;
            Bsw[bsw_index(k, n)] = f2bf(W_det[idx]);
        }
    }
}

// ---------------------------------------------------------------------------
// fused: gather+mean into LDS A-tile (bf16), then MFMA GEMM + ReLU.
// One block (4 waves) per 16-row M-tile. 1250 blocks.
//   Phase 1: wave w gathers batch elems m = w*4..w*4+3 (84 independent 16B
//            loads in flight per wave), writes [self | mean0 | mean1] bf16
//            rows into padded LDS tile.
//   Phase 2: wave w computes n-tiles {w, w+4}: 24 kt x 2 MFMA from LDS A
//            fragments (ds_read_b128) and L2-resident swizzled B.
// ---------------------------------------------------------------------------
__global__ __launch_bounds__(256, 4) void fused(const int* __restrict__ nodes,
                                                const int* __restrict__ neigh_idx,
                                                const float* __restrict__ features,
                                                const unsigned short* __restrict__ Bsw,
                                                float* __restrict__ out) {
    __shared__ unsigned short As[16 * AROW];   // 24832 B

    const int blk  = blockIdx.x;               // m-tile id (0..1249)
    const int w    = threadIdx.x >> 6;         // wave 0..3
    const int lane = threadIdx.x & 63;
    const float4* F4 = (const float4*)features;
    const float inv = 1.0f / (float)KNEI;

    // ---- Phase 1: gather + mean ----
    #pragma unroll
    for (int e = 0; e < 4; ++e) {
        const int m = w * 4 + e;               // row in tile
        const int b = blk * 16 + m;            // batch element
        const int self = nodes[b];
        const int* i0 = neigh_idx + (size_t)b * KNEI;
        const int* i1 = neigh_idx + (size_t)(BATCH + b) * KNEI;

        float4 sf = F4[(size_t)self * 64 + lane];
        float4 s0 = make_float4(0.f, 0.f, 0.f, 0.f);
        float4 s1 = make_float4(0.f, 0.f, 0.f, 0.f);
        #pragma unroll
        for (int k = 0; k < KNEI; ++k) {
            float4 v = F4[(size_t)i0[k] * 64 + lane];
            s0.x += v.x; s0.y += v.y; s0.z += v.z; s0.w += v.w;
        }
        #pragma unroll
        for (int k = 0; k < KNEI; ++k) {
            float4 v = F4[(size_t)i1[k] * 64 + lane];
            s1.x += v.x; s1.y += v.y; s1.z += v.z; s1.w += v.w;
        }
        ushort4* row = (ushort4*)(As + m * AROW);
        row[lane]       = pack4(sf.x, sf.y, sf.z, sf.w);
        row[64 + lane]  = pack4(s0.x * inv, s0.y * inv, s0.z * inv, s0.w * inv);
        row[128 + lane] = pack4(s1.x * inv, s1.y * inv, s1.z * inv, s1.w * inv);
    }
    __syncthreads();

    // ---- Phase 2: GEMM + ReLU ----
    const int quad = lane >> 4;
    const int l16  = lane & 15;
    const unsigned short* a_base = As + l16 * AROW + quad * 8;

    f32x4 acc0 = (f32x4){0.f, 0.f, 0.f, 0.f};
    f32x4 acc1 = (f32x4){0.f, 0.f, 0.f, 0.f};
    const int nt0 = w, nt1 = w + 4;

    #pragma unroll
    for (int kt = 0; kt < 24; ++kt) {
        bf16x8 a = *(const bf16x8*)(a_base + kt * 32);
        const unsigned short* bk = Bsw + ((size_t)(kt * 8) * 64 + lane) * 8;
        bf16x8 b0 = *(const bf16x8*)(bk + (size_t)nt0 * 64 * 8);
        bf16x8 b1 = *(const bf16x8*)(bk + (size_t)nt1 * 64 * 8);
        acc0 = __builtin_amdgcn_mfma_f32_16x16x32_bf16(a, b0, acc0, 0, 0, 0);
        acc1 = __builtin_amdgcn_mfma_f32_16x16x32_bf16(a, b1, acc1, 0, 0, 0);
    }

    float* orow = out + (size_t)(blk * 16) * HID;
    #pragma unroll
    for (int r = 0; r < 4; ++r) {
        const int row = quad * 4 + r;
        float v0 = acc0[r];
        float v1 = acc1[r];
        orow[(size_t)row * HID + nt0 * 16 + l16] = v0 > 0.f ? v0 : 0.f;
        orow[(size_t)row * HID + nt1 * 16 + l16] = v1 > 0.f ? v1 : 0.f;
    }
}

extern "C" void kernel_launch(void* const* d_in, const int* in_sizes, int n_in,
                              void* d_out, int out_size, void* d_ws, size_t ws_size,
                              hipStream_t stream) {
    const int*   nodes     = (const int*)d_in[0];
    const int*   neigh_idx = (const int*)d_in[1];
    const float* features  = (const float*)d_in[2];
    const float* W_stc     = (const float*)d_in[3];
    const float* W_det     = (const float*)d_in[4];
    float* out = (float*)d_out;

    unsigned short* Bsw = (unsigned short*)d_ws;   // 768*128 bf16 = 192 KB

    prep_B<<<34, 256, 0, stream>>>(W_stc, W_det, Bsw);
    fused<<<BATCH / 16, 256, 0, stream>>>(nodes, neigh_idx, features, Bsw, out);
}